// Round 1
// baseline (383.339 us; speedup 1.0000x reference)
//
#include <hip/hip_runtime.h>
#include <hip/hip_bf16.h>

#define NSTEP 50
#define S51 51
#define HID 128
#define MT 128                    // rows per tile
#define NROWS (16384 * S51)       // 835584
#define NTILES (NROWS / MT)       // 6528
#define MAIN_GRID 1632            // NTILES / 4 -> 4 tiles per block
#define LDA 136                   // Abuf row stride in bf16 elems (272B: 16B-aligned, conflict-free)

typedef __attribute__((ext_vector_type(8))) short short8;
typedef __attribute__((ext_vector_type(4))) float floatx4;

__device__ __forceinline__ unsigned pk_bf16(float a, float b) {
    __hip_bfloat162 t = __float22bfloat162_rn(make_float2(a, b));
    unsigned u;
    __builtin_memcpy(&u, &t, 4);
    return u;
}
__device__ __forceinline__ float bf2f(unsigned short us) {
    return __uint_as_float(((unsigned)us) << 16);
}

__global__ void init_out_kernel(const float* __restrict__ h, float* __restrict__ out) {
    int i = blockIdx.x * blockDim.x + threadIdx.x;
    out[i] = h[i];
}

// wf[kc][it] element j holds W[kc*32 + quad*8 + j][wave_i*64 + it*16 + l15]  (A-operand layout)
__device__ __forceinline__ void mfma_layer(const short8 (&wf)[4][4],
                                           const unsigned short (*Ab)[LDA],
                                           int wave_j, int l15, int quad,
                                           floatx4 (&acc)[4][2]) {
#pragma unroll
    for (int it = 0; it < 4; ++it)
#pragma unroll
        for (int jt = 0; jt < 2; ++jt) {
            floatx4 z = {0.f, 0.f, 0.f, 0.f};
            acc[it][jt] = z;
        }
#pragma unroll
    for (int kc = 0; kc < 4; ++kc) {
        short8 bfr[2];
#pragma unroll
        for (int jt = 0; jt < 2; ++jt)
            bfr[jt] = *(const short8*)(&Ab[wave_j * 32 + jt * 16 + l15][kc * 32 + quad * 8]);
#pragma unroll
        for (int it = 0; it < 4; ++it)
#pragma unroll
            for (int jt = 0; jt < 2; ++jt)
                acc[it][jt] = __builtin_amdgcn_mfma_f32_16x16x32_bf16(
                    wf[kc][it], bfr[jt], acc[it][jt], 0, 0, 0);
    }
}

// D[i][j] = a_next[j][i]; lane holds j = l15 (col), i = quad*4+reg (row). Write 4 consecutive
// hidden elems (packed bf16 x4 = 8B) into row-major activation buffer.
__device__ __forceinline__ void epilogue_layer(const floatx4 (&acc)[4][2], const float* bs,
                                               unsigned short (*Ab)[LDA],
                                               int wave_i, int wave_j, int l15, int quad) {
#pragma unroll
    for (int it = 0; it < 4; ++it) {
        const int ib = wave_i * 64 + it * 16 + quad * 4;
        const floatx4 bv = *(const floatx4*)(&bs[ib]);
#pragma unroll
        for (int jt = 0; jt < 2; ++jt) {
            const int j = wave_j * 32 + jt * 16 + l15;
            float v0 = fmaxf(acc[it][jt][0] + bv[0], 0.0f);
            float v1 = fmaxf(acc[it][jt][1] + bv[1], 0.0f);
            float v2 = fmaxf(acc[it][jt][2] + bv[2], 0.0f);
            float v3 = fmaxf(acc[it][jt][3] + bv[3], 0.0f);
            unsigned long long pv =
                ((unsigned long long)pk_bf16(v2, v3) << 32) | (unsigned long long)pk_bf16(v0, v1);
            *(unsigned long long*)(&Ab[j][ib]) = pv;
        }
    }
}

__launch_bounds__(512, 2)
__global__ void monotonic_fused(const float* __restrict__ x, const float* __restrict__ h,
                                const float* __restrict__ w1, const float* __restrict__ b1,
                                const float* __restrict__ w2, const float* __restrict__ b2,
                                const float* __restrict__ w3, const float* __restrict__ b3,
                                const float* __restrict__ w4, const float* __restrict__ b4,
                                float* __restrict__ out) {
    __shared__ unsigned short Abuf[MT][LDA];   // activations, row-major [row][k], bf16
    __shared__ float b2s[HID], b3s[HID];
    __shared__ float fs[S51 + 1], ts[S51 + 1];

    const int tid = threadIdx.x;
    const int lane = tid & 63;
    const int wave = tid >> 6;      // 0..7
    const int wave_i = wave & 1;    // hidden-out half (64 wide)
    const int wave_j = wave >> 1;   // row quarter (32 rows)
    const int l15 = lane & 15;
    const int quad = lane >> 4;

    if (tid < HID) { b2s[tid] = b2[tid]; b3s[tid] = b3[tid]; }
    if (tid < S51) {
        // Faithful port of compute_cc_weights (reference formula)
        const float PI50 = 0.06283185307179586f;  // pi/50
        float acc = 1.0f;                          // i=0 term (W[0]=1)
        for (int i = 2; i <= 50; i += 2) {
            int m = (i * tid) % 100;               // exact argument reduction (period 2*pi)
            acc += (2.0f / (1.0f - (float)(i * i))) * cosf((float)m * PI50);
        }
        float ccw = acc * 0.04f * ((tid == 0 || tid == NSTEP) ? 0.5f : 1.0f);  // * 2/50, col scale
        fs[tid] = ccw * 0.5f;                                   // folds the (x-x0)*0.5 factor
        ts[tid] = (cosf((float)tid * PI50) + 1.0f) * 0.5f;      // (steps+1)/2
    }

    // per-thread layer1/layer4 weight caches: thread owns k-chunk k0..k0+7, rows rb..rb+3
    const int kk = tid & 15;
    const int k0 = kk * 8;
    const int rb = (tid >> 4) * 4;
    float w10r[8], w11r[8], b1r[8], w4r[8];
#pragma unroll
    for (int e = 0; e < 8; ++e) {
        w10r[e] = w1[k0 + e];
        w11r[e] = w1[HID + k0 + e];
        b1r[e] = b1[k0 + e];
        w4r[e] = w4[k0 + e];
    }
    const float b4v = b4[0];

    // gather W2^T / W3^T fragments into registers (once per block)
    short8 w2f[4][4], w3f[4][4];
#pragma unroll
    for (int kc = 0; kc < 4; ++kc) {
#pragma unroll
        for (int it = 0; it < 4; ++it) {
            const int i = wave_i * 64 + it * 16 + l15;
            const int kb = kc * 32 + quad * 8;
            union { short8 s; unsigned u[4]; } c2, c3;
#pragma unroll
            for (int e2 = 0; e2 < 4; ++e2) {
                float a0 = w2[(kb + 2 * e2) * HID + i];
                float a1 = w2[(kb + 2 * e2 + 1) * HID + i];
                float g0 = w3[(kb + 2 * e2) * HID + i];
                float g1 = w3[(kb + 2 * e2 + 1) * HID + i];
                c2.u[e2] = pk_bf16(a0, a1);
                c3.u[e2] = pk_bf16(g0, g1);
            }
            w2f[kc][it] = c2.s;
            w3f[kc][it] = c3.s;
        }
    }
    __syncthreads();

    for (int tile = blockIdx.x; tile < NTILES; tile += MAIN_GRID) {
        const int rowbase = tile * MT;

        // ---- layer 1: a1 = relu([X,h] @ w1 + b1), bf16 -> LDS ----
        {
            int grow = rowbase + rb;
            int bb = grow / S51;
            int ss = grow - bb * S51;
#pragma unroll
            for (int rr = 0; rr < 4; ++rr) {
                float xb = x[bb], hb = h[bb];
                float X = xb * ts[ss];
                unsigned vv[4];
#pragma unroll
                for (int e2 = 0; e2 < 4; ++e2) {
                    float u0 = fmaxf(fmaf(X, w10r[2 * e2], fmaf(hb, w11r[2 * e2], b1r[2 * e2])), 0.0f);
                    float u1 = fmaxf(fmaf(X, w10r[2 * e2 + 1], fmaf(hb, w11r[2 * e2 + 1], b1r[2 * e2 + 1])), 0.0f);
                    vv[e2] = pk_bf16(u0, u1);
                }
                *(uint4*)(&Abuf[rb + rr][k0]) = make_uint4(vv[0], vv[1], vv[2], vv[3]);
                ++ss;
                if (ss == S51) { ss = 0; ++bb; }
            }
        }
        __syncthreads();

        floatx4 acc[4][2];

        // ---- layer 2 ----
        mfma_layer(w2f, Abuf, wave_j, l15, quad, acc);
        __syncthreads();
        epilogue_layer(acc, b2s, Abuf, wave_i, wave_j, l15, quad);
        __syncthreads();

        // ---- layer 3 ----
        mfma_layer(w3f, Abuf, wave_j, l15, quad, acc);
        __syncthreads();
        epilogue_layer(acc, b3s, Abuf, wave_i, wave_j, l15, quad);
        __syncthreads();

        // ---- layer 4: dot(a3, w4) + b4 -> elu + 1 -> quadrature accumulate ----
        {
            float ps[4];
#pragma unroll
            for (int rr = 0; rr < 4; ++rr) {
                short8 v = *(const short8*)(&Abuf[rb + rr][k0]);
                float sacc = 0.0f;
#pragma unroll
                for (int e = 0; e < 8; ++e)
                    sacc = fmaf(bf2f((unsigned short)v[e]), w4r[e], sacc);
                ps[rr] = sacc;
            }
#pragma unroll
            for (int m = 1; m < 16; m <<= 1) {
#pragma unroll
                for (int rr = 0; rr < 4; ++rr)
                    ps[rr] += __shfl_xor(ps[rr], m, 64);
            }
            if (l15 == 0) {
                int grow = rowbase + rb;
                int bb = grow / S51;
                int ss = grow - bb * S51;
#pragma unroll
                for (int rr = 0; rr < 4; ++rr) {
                    float u = ps[rr] + b4v;
                    float dz = u > 0.0f ? u + 1.0f : __expf(u);  // elu(u)+1
                    atomicAdd(&out[bb], dz * fs[ss] * x[bb]);
                    ++ss;
                    if (ss == S51) { ss = 0; ++bb; }
                }
            }
        }
        __syncthreads();
    }
}

extern "C" void kernel_launch(void* const* d_in, const int* in_sizes, int n_in,
                              void* d_out, int out_size, void* d_ws, size_t ws_size,
                              hipStream_t stream) {
    const float* x  = (const float*)d_in[0];
    const float* h  = (const float*)d_in[1];
    const float* w1 = (const float*)d_in[2];
    const float* b1 = (const float*)d_in[3];
    const float* w2 = (const float*)d_in[4];
    const float* b2 = (const float*)d_in[5];
    const float* w3 = (const float*)d_in[6];
    const float* b3 = (const float*)d_in[7];
    const float* w4 = (const float*)d_in[8];
    const float* b4 = (const float*)d_in[9];
    float* out = (float*)d_out;

    init_out_kernel<<<16384 / 256, 256, 0, stream>>>(h, out);
    monotonic_fused<<<MAIN_GRID, 512, 0, stream>>>(x, h, w1, b1, w2, b2, w3, b3, w4, b4, out);
}

// Round 2
// 214.806 us; speedup vs baseline: 1.7846x; 1.7846x over previous
//
#include <hip/hip_runtime.h>
#include <hip/hip_bf16.h>

#define NSTEP 50
#define S51 51
#define HID 128
#define MT 128                 // rows per tile
#define LDA 136                // Abuf row stride in bf16 elems (272B; 16B-aligned; rows advance 4 banks)
#define BPB 16                 // batch elems per block (block owns them fully -> no global atomics)
#define RPB (BPB * S51)        // 816 valid rows per block
#define NTILE 7                // ceil(816/128): 896 rows, 80 masked
#define GRID (16384 / BPB)     // 1024 blocks

typedef __attribute__((ext_vector_type(8))) short short8;
typedef __attribute__((ext_vector_type(4))) float floatx4;

__device__ __forceinline__ unsigned pk_bf16(float a, float b) {
    __hip_bfloat162 t = __float22bfloat162_rn(make_float2(a, b));
    unsigned u;
    __builtin_memcpy(&u, &t, 4);
    return u;
}
__device__ __forceinline__ float bf2f(unsigned short us) {
    return __uint_as_float(((unsigned)us) << 16);
}

// Weights for both 128x128 layers live in VGPRs, split 8 ways: wave wi owns hidden
// rows [wi*16, wi*16+16). w2f[kc] element e holds W[kc*32+quad*8+e][wi*16+l15]
// (MFMA A-operand layout, M=16). 4+4 frags = 32 VGPRs/thread.
__launch_bounds__(512, 4)
__global__ void monotonic_fused(const float* __restrict__ x, const float* __restrict__ h,
                                const float* __restrict__ w1, const float* __restrict__ b1,
                                const float* __restrict__ w2, const float* __restrict__ b2,
                                const float* __restrict__ w3, const float* __restrict__ b3,
                                const float* __restrict__ w4, const float* __restrict__ b4,
                                float* __restrict__ out) {
    __shared__ unsigned short Abuf[2][MT][LDA];  // double-buffered activations (69.6 KB)
    __shared__ float w1s[2 * HID], b1s[HID], w4s[HID];
    __shared__ float b2s[HID], b3s[HID];
    __shared__ float fs[S51], ts[S51];
    __shared__ float xs[BPB], hs[BPB], osum[BPB];

    const int tid = threadIdx.x;
    const int lane = tid & 63;
    const int wi = tid >> 6;       // wave 0..7 = hidden-out 16-row slice
    const int l15 = lane & 15;
    const int quad = lane >> 4;
    const int kcol = tid & 15;     // k-chunk owner (L1/L4): 8 cols
    const int k0 = kcol * 8;
    const int rb = (tid >> 4) * 4; // row group: 4 rows, covers 0..127 over 512 threads

    // ---- stage small tensors to LDS ----
    if (tid < 2 * HID) w1s[tid] = w1[tid];
    if (tid < HID) { b1s[tid] = b1[tid]; w4s[tid] = w4[tid]; b2s[tid] = b2[tid]; b3s[tid] = b3[tid]; }
    if (tid < BPB) {
        xs[tid] = x[blockIdx.x * BPB + tid];
        hs[tid] = h[blockIdx.x * BPB + tid];
        osum[tid] = 0.0f;
    }
    if (tid < S51) {
        // Faithful port of compute_cc_weights (verified R1, absmax 0.031)
        const float PI50 = 0.06283185307179586f;  // pi/50
        float acc = 1.0f;
        for (int i = 2; i <= 50; i += 2) {
            int m = (i * tid) % 100;  // exact argument reduction
            acc += (2.0f / (1.0f - (float)(i * i))) * cosf((float)m * PI50);
        }
        float ccw = acc * 0.04f * ((tid == 0 || tid == NSTEP) ? 0.5f : 1.0f);
        fs[tid] = ccw * 0.5f;                               // folds the (x-x0)*0.5 factor
        ts[tid] = (cosf((float)tid * PI50) + 1.0f) * 0.5f;  // (steps+1)/2
    }
    const float b4v = b4[0];

    // ---- gather W2^T / W3^T fragments (once per block; coalesced over l15) ----
    short8 w2f[4], w3f[4];
#pragma unroll
    for (int kc = 0; kc < 4; ++kc) {
        const int i = wi * 16 + l15;
        const int kb = kc * 32 + quad * 8;
        union { short8 s; unsigned u[4]; } c2, c3;
#pragma unroll
        for (int e2 = 0; e2 < 4; ++e2) {
            c2.u[e2] = pk_bf16(w2[(kb + 2 * e2) * HID + i], w2[(kb + 2 * e2 + 1) * HID + i]);
            c3.u[e2] = pk_bf16(w3[(kb + 2 * e2) * HID + i], w3[(kb + 2 * e2 + 1) * HID + i]);
        }
        w2f[kc] = c2.s;
        w3f[kc] = c3.s;
    }
    __syncthreads();

    // ---- layer-1 for tile 0 -> buf 0 ----
    {
#pragma unroll
        for (int rr = 0; rr < 4; ++rr) {
            int lrc = rb + rr;  // tile 0: rows 0..127 all valid
            unsigned bbl = (unsigned)lrc / 51u;
            int ss = lrc - (int)bbl * 51;
            float X = xs[bbl] * ts[ss], hb = hs[bbl];
            unsigned vv[4];
#pragma unroll
            for (int e2 = 0; e2 < 4; ++e2) {
                float u0 = fmaxf(fmaf(X, w1s[k0 + 2 * e2], fmaf(hb, w1s[HID + k0 + 2 * e2], b1s[k0 + 2 * e2])), 0.0f);
                float u1 = fmaxf(fmaf(X, w1s[k0 + 2 * e2 + 1], fmaf(hb, w1s[HID + k0 + 2 * e2 + 1], b1s[k0 + 2 * e2 + 1])), 0.0f);
                vv[e2] = pk_bf16(u0, u1);
            }
            *(uint4*)(&Abuf[0][rb + rr][k0]) = make_uint4(vv[0], vv[1], vv[2], vv[3]);
        }
    }
    __syncthreads();

    const floatx4 bv2 = *(const floatx4*)(&b2s[wi * 16 + quad * 4]);
    const floatx4 bv3 = *(const floatx4*)(&b3s[wi * 16 + quad * 4]);

    for (int t = 0; t < NTILE; ++t) {
        const int bA = t & 1, bB = bA ^ 1;

        // ---- layer 2: MFMA read bufA, relu+pack write bufB ----
        {
            floatx4 acc[8];
#pragma unroll
            for (int jt = 0; jt < 8; ++jt) { floatx4 z = {0.f, 0.f, 0.f, 0.f}; acc[jt] = z; }
#pragma unroll
            for (int kc = 0; kc < 4; ++kc) {
#pragma unroll
                for (int jt = 0; jt < 8; ++jt) {
                    short8 bfr = *(const short8*)(&Abuf[bA][jt * 16 + l15][kc * 32 + quad * 8]);
                    acc[jt] = __builtin_amdgcn_mfma_f32_16x16x32_bf16(w2f[kc], bfr, acc[jt], 0, 0, 0);
                }
            }
            __syncthreads();
#pragma unroll
            for (int jt = 0; jt < 8; ++jt) {
                float v0 = fmaxf(acc[jt][0] + bv2[0], 0.0f);
                float v1 = fmaxf(acc[jt][1] + bv2[1], 0.0f);
                float v2 = fmaxf(acc[jt][2] + bv2[2], 0.0f);
                float v3 = fmaxf(acc[jt][3] + bv2[3], 0.0f);
                unsigned long long pv =
                    ((unsigned long long)pk_bf16(v2, v3) << 32) | (unsigned long long)pk_bf16(v0, v1);
                *(unsigned long long*)(&Abuf[bB][jt * 16 + l15][wi * 16 + quad * 4]) = pv;
            }
        }
        __syncthreads();

        // ---- layer 3: MFMA read bufB, relu+pack write bufA ----
        {
            floatx4 acc[8];
#pragma unroll
            for (int jt = 0; jt < 8; ++jt) { floatx4 z = {0.f, 0.f, 0.f, 0.f}; acc[jt] = z; }
#pragma unroll
            for (int kc = 0; kc < 4; ++kc) {
#pragma unroll
                for (int jt = 0; jt < 8; ++jt) {
                    short8 bfr = *(const short8*)(&Abuf[bB][jt * 16 + l15][kc * 32 + quad * 8]);
                    acc[jt] = __builtin_amdgcn_mfma_f32_16x16x32_bf16(w3f[kc], bfr, acc[jt], 0, 0, 0);
                }
            }
            __syncthreads();
#pragma unroll
            for (int jt = 0; jt < 8; ++jt) {
                float v0 = fmaxf(acc[jt][0] + bv3[0], 0.0f);
                float v1 = fmaxf(acc[jt][1] + bv3[1], 0.0f);
                float v2 = fmaxf(acc[jt][2] + bv3[2], 0.0f);
                float v3 = fmaxf(acc[jt][3] + bv3[3], 0.0f);
                unsigned long long pv =
                    ((unsigned long long)pk_bf16(v2, v3) << 32) | (unsigned long long)pk_bf16(v0, v1);
                *(unsigned long long*)(&Abuf[bA][jt * 16 + l15][wi * 16 + quad * 4]) = pv;
            }
        }
        __syncthreads();

        // ---- layer 4 (read bufA) in parallel with layer 1 of tile t+1 (write bufB) ----
        {
            float ps[4];
#pragma unroll
            for (int rr = 0; rr < 4; ++rr) {
                short8 v = *(const short8*)(&Abuf[bA][rb + rr][k0]);
                float sacc = 0.0f;
#pragma unroll
                for (int e = 0; e < 8; ++e)
                    sacc = fmaf(bf2f((unsigned short)v[e]), w4s[k0 + e], sacc);
                ps[rr] = sacc;
            }
#pragma unroll
            for (int m = 1; m < 16; m <<= 1) {
#pragma unroll
                for (int rr = 0; rr < 4; ++rr)
                    ps[rr] += __shfl_xor(ps[rr], m, 64);
            }
            if (l15 == 0) {
                // merge equal-bbl runs -> <=2 LDS atomics per lane
                float run = 0.0f;
                int runb = -1;
#pragma unroll
                for (int rr = 0; rr < 4; ++rr) {
                    int lr = t * MT + rb + rr;
                    int lrc = lr < RPB ? lr : RPB - 1;
                    unsigned bbl = (unsigned)lrc / 51u;
                    int ss = lrc - (int)bbl * 51;
                    float u = ps[rr] + b4v;
                    float dz = u > 0.0f ? u + 1.0f : __expf(u);  // elu(u)+1
                    float val = (lr < RPB) ? dz * fs[ss] : 0.0f;
                    if ((int)bbl == runb) {
                        run += val;
                    } else {
                        if (runb >= 0) atomicAdd(&osum[runb], run);
                        run = val; runb = (int)bbl;
                    }
                }
                atomicAdd(&osum[runb], run);
            }

            if (t + 1 < NTILE) {
#pragma unroll
                for (int rr = 0; rr < 4; ++rr) {
                    int lr = (t + 1) * MT + rb + rr;
                    int lrc = lr < RPB ? lr : RPB - 1;
                    unsigned bbl = (unsigned)lrc / 51u;
                    int ss = lrc - (int)bbl * 51;
                    float X = xs[bbl] * ts[ss], hb = hs[bbl];
                    unsigned vv[4];
#pragma unroll
                    for (int e2 = 0; e2 < 4; ++e2) {
                        float u0 = fmaxf(fmaf(X, w1s[k0 + 2 * e2], fmaf(hb, w1s[HID + k0 + 2 * e2], b1s[k0 + 2 * e2])), 0.0f);
                        float u1 = fmaxf(fmaf(X, w1s[k0 + 2 * e2 + 1], fmaf(hb, w1s[HID + k0 + 2 * e2 + 1], b1s[k0 + 2 * e2 + 1])), 0.0f);
                        vv[e2] = pk_bf16(u0, u1);
                    }
                    *(uint4*)(&Abuf[bB][rb + rr][k0]) = make_uint4(vv[0], vv[1], vv[2], vv[3]);
                }
            }
        }
        __syncthreads();
    }

    // block fully owns its 16 batch elements: plain store, no global atomics
    if (tid < BPB) out[blockIdx.x * BPB + tid] = hs[tid] + osum[tid] * xs[tid];
}

extern "C" void kernel_launch(void* const* d_in, const int* in_sizes, int n_in,
                              void* d_out, int out_size, void* d_ws, size_t ws_size,
                              hipStream_t stream) {
    const float* x  = (const float*)d_in[0];
    const float* h  = (const float*)d_in[1];
    const float* w1 = (const float*)d_in[2];
    const float* b1 = (const float*)d_in[3];
    const float* w2 = (const float*)d_in[4];
    const float* b2 = (const float*)d_in[5];
    const float* w3 = (const float*)d_in[6];
    const float* b3 = (const float*)d_in[7];
    const float* w4 = (const float*)d_in[8];
    const float* b4 = (const float*)d_in[9];
    float* out = (float*)d_out;

    monotonic_fused<<<GRID, 512, 0, stream>>>(x, h, w1, b1, w2, b2, w3, b3, w4, b4, out);
}

// Round 3
// 206.424 us; speedup vs baseline: 1.8570x; 1.0406x over previous
//
#include <hip/hip_runtime.h>
#include <hip/hip_bf16.h>

#define NSTEP 50
#define S51 51
#define HID 128
#define MT 128                 // rows per tile
#define LDA 136                // row stride in bf16 elems (272B; 16B-aligned; rows advance 4 banks)
#define BPB 16                 // batch elems per block (block owns them -> no global atomics)
#define RPB (BPB * S51)        // 816 valid rows per block
#define NTILE 7                // ceil(816/128)
#define GRID (16384 / BPB)     // 1024 blocks

typedef __attribute__((ext_vector_type(8))) short short8;
typedef __attribute__((ext_vector_type(4))) float floatx4;
typedef __attribute__((ext_vector_type(16))) float floatx16;

__device__ __forceinline__ unsigned pk_bf16(float a, float b) {
    __hip_bfloat162 t = __float22bfloat162_rn(make_float2(a, b));
    unsigned u;
    __builtin_memcpy(&u, &t, 4);
    return u;
}

// Wave layout: 8 waves = 4 (mi: 32-hidden slice) x 2 (nj: 64-row half).
// 32x32x16 MFMA: A = W^T in registers (8 frags x 4 VGPR x 2 layers = 64 VGPR),
// B = activations from LDS (each wave reads only its own 64 rows -> half the
// LDS traffic of the 16x16 M-split-8 scheme). Layer 4 fused into L3 epilogue.
__launch_bounds__(512, 4)
__global__ void monotonic_fused(const float* __restrict__ x, const float* __restrict__ h,
                                const float* __restrict__ w1, const float* __restrict__ b1,
                                const float* __restrict__ w2, const float* __restrict__ b2,
                                const float* __restrict__ w3, const float* __restrict__ b3,
                                const float* __restrict__ w4, const float* __restrict__ b4,
                                float* __restrict__ out) {
    __shared__ unsigned short A1[MT][LDA];   // a1 (L1 out, L2 in)
    __shared__ unsigned short A2[MT][LDA];   // a2 (L2 out, L3 in)
    __shared__ float w1s[2 * HID], b1s[HID], b2s[HID], b3s[HID], w4s[HID];
    __shared__ float fs[S51], ts[S51];
    __shared__ float xs[BPB], hs[BPB], osum[BPB];
    __shared__ float posum[MT];              // per-row fused-L4 partial dots

    const int tid = threadIdx.x;
    const int lane = tid & 63;
    const int wv = tid >> 6;
    const int mi = wv & 3;        // hidden 32-slice
    const int nj = wv >> 2;       // row 64-half
    const int l31 = lane & 31;
    const int hi = lane >> 5;
    const int k0 = (tid & 15) * 8;   // L1 writer: k-chunk
    const int rb = (tid >> 4) * 4;   // L1 writer: row group

    // ---- stage small tensors ----
    if (tid < 2 * HID) w1s[tid] = w1[tid];
    if (tid < HID) {
        b1s[tid] = b1[tid]; b2s[tid] = b2[tid]; b3s[tid] = b3[tid]; w4s[tid] = w4[tid];
        posum[tid] = 0.0f;
    }
    if (tid < BPB) {
        xs[tid] = x[blockIdx.x * BPB + tid];
        hs[tid] = h[blockIdx.x * BPB + tid];
        osum[tid] = 0.0f;
    }
    if (tid < S51) {
        // Faithful port of compute_cc_weights (verified R1/R2, absmax 0.031)
        const float PI50 = 0.06283185307179586f;  // pi/50
        float acc = 1.0f;
        for (int i = 2; i <= 50; i += 2) {
            int m = (i * tid) % 100;  // exact argument reduction
            acc += (2.0f / (1.0f - (float)(i * i))) * cosf((float)m * PI50);
        }
        float ccw = acc * 0.04f * ((tid == 0 || tid == NSTEP) ? 0.5f : 1.0f);
        fs[tid] = ccw * 0.5f;                               // folds the (x-x0)*0.5 factor
        ts[tid] = (cosf((float)tid * PI50) + 1.0f) * 0.5f;  // (steps+1)/2
    }
    const float b4v = b4[0];

    // ---- gather W2^T / W3^T A-operand fragments (global, coalesced over l31) ----
    // frag[kc] elem e = W[kc*16 + hi*8 + e][mi*32 + l31]
    short8 w2f[8], w3f[8];
    {
        const int irow = mi * 32 + l31;
#pragma unroll
        for (int kc = 0; kc < 8; ++kc) {
            const int kb = kc * 16 + hi * 8;
            union { short8 s; unsigned u[4]; } c2, c3;
#pragma unroll
            for (int e2 = 0; e2 < 4; ++e2) {
                c2.u[e2] = pk_bf16(w2[(kb + 2 * e2) * HID + irow], w2[(kb + 2 * e2 + 1) * HID + irow]);
                c3.u[e2] = pk_bf16(w3[(kb + 2 * e2) * HID + irow], w3[(kb + 2 * e2 + 1) * HID + irow]);
            }
            w2f[kc] = c2.s;
            w3f[kc] = c3.s;
        }
    }
    __syncthreads();

    // ---- L1 for tile 0 -> A1 ----
#pragma unroll
    for (int rr = 0; rr < 4; ++rr) {
        int lrc = rb + rr;  // tile 0 rows all valid
        unsigned bbl = (unsigned)lrc / 51u;
        int ss = lrc - (int)bbl * 51;
        float X = xs[bbl] * ts[ss], hb = hs[bbl];
        unsigned vv[4];
#pragma unroll
        for (int e2 = 0; e2 < 4; ++e2) {
            float u0 = fmaxf(fmaf(X, w1s[k0 + 2 * e2], fmaf(hb, w1s[HID + k0 + 2 * e2], b1s[k0 + 2 * e2])), 0.0f);
            float u1 = fmaxf(fmaf(X, w1s[k0 + 2 * e2 + 1], fmaf(hb, w1s[HID + k0 + 2 * e2 + 1], b1s[k0 + 2 * e2 + 1])), 0.0f);
            vv[e2] = pk_bf16(u0, u1);
        }
        *(uint4*)(&A1[rb + rr][k0]) = make_uint4(vv[0], vv[1], vv[2], vv[3]);
    }
    __syncthreads();

    const int j0 = nj * 64 + l31;  // this wave's first-row index (jt=0); jt=1 at +32

    for (int t = 0; t < NTILE; ++t) {
        // ================= P1: layer 2 (read A1) =================
        floatx16 acc0 = {0.f,0.f,0.f,0.f,0.f,0.f,0.f,0.f,0.f,0.f,0.f,0.f,0.f,0.f,0.f,0.f};
        floatx16 acc1 = acc0;
        {
            const unsigned short* r0 = &A1[j0][0];
            const unsigned short* r1 = &A1[j0 + 32][0];
#pragma unroll
            for (int kc = 0; kc < 8; ++kc) {
                short8 bf0 = *(const short8*)(r0 + kc * 16 + hi * 8);
                short8 bf1 = *(const short8*)(r1 + kc * 16 + hi * 8);
                acc0 = __builtin_amdgcn_mfma_f32_32x32x16_bf16(w2f[kc], bf0, acc0, 0, 0, 0);
                acc1 = __builtin_amdgcn_mfma_f32_32x32x16_bf16(w3f[0] * 0 + w2f[kc], bf1, acc1, 0, 0, 0);
            }
        }
        // consume previous tile's fused-L4 partials while MFMAs drain
        if (t > 0 && tid < MT) {
            int lr = (t - 1) * MT + tid;
            float u = posum[tid] + b4v;
            posum[tid] = 0.0f;
            if (lr < RPB) {
                unsigned bbl = (unsigned)lr / 51u;
                int ss = lr - (int)bbl * 51;
                float dz = u > 0.0f ? u + 1.0f : __expf(u);  // elu(u)+1
                atomicAdd(&osum[bbl], dz * fs[ss]);
            }
        }
        // epilogue: relu(acc + b2) -> A2[j][i] (bf16, 4 consecutive i per store)
#pragma unroll
        for (int g = 0; g < 4; ++g) {
            const int i0 = mi * 32 + 8 * g + 4 * hi;
            const floatx4 bb = *(const floatx4*)(&b2s[i0]);
            float v0 = fmaxf(acc0[4 * g + 0] + bb[0], 0.0f);
            float v1 = fmaxf(acc0[4 * g + 1] + bb[1], 0.0f);
            float v2 = fmaxf(acc0[4 * g + 2] + bb[2], 0.0f);
            float v3 = fmaxf(acc0[4 * g + 3] + bb[3], 0.0f);
            *(unsigned long long*)(&A2[j0][i0]) =
                ((unsigned long long)pk_bf16(v2, v3) << 32) | (unsigned long long)pk_bf16(v0, v1);
            v0 = fmaxf(acc1[4 * g + 0] + bb[0], 0.0f);
            v1 = fmaxf(acc1[4 * g + 1] + bb[1], 0.0f);
            v2 = fmaxf(acc1[4 * g + 2] + bb[2], 0.0f);
            v3 = fmaxf(acc1[4 * g + 3] + bb[3], 0.0f);
            *(unsigned long long*)(&A2[j0 + 32][i0]) =
                ((unsigned long long)pk_bf16(v2, v3) << 32) | (unsigned long long)pk_bf16(v0, v1);
        }
        __syncthreads();

        // ================= P2: layer 3 (read A2) + fused layer 4 + L1(t+1) =================
        floatx16 c0 = {0.f,0.f,0.f,0.f,0.f,0.f,0.f,0.f,0.f,0.f,0.f,0.f,0.f,0.f,0.f,0.f};
        floatx16 c1 = c0;
        {
            const unsigned short* r0 = &A2[j0][0];
            const unsigned short* r1 = &A2[j0 + 32][0];
#pragma unroll
            for (int kc = 0; kc < 8; ++kc) {
                short8 bf0 = *(const short8*)(r0 + kc * 16 + hi * 8);
                short8 bf1 = *(const short8*)(r1 + kc * 16 + hi * 8);
                c0 = __builtin_amdgcn_mfma_f32_32x32x16_bf16(w3f[kc], bf0, c0, 0, 0, 0);
                c1 = __builtin_amdgcn_mfma_f32_32x32x16_bf16(w3f[kc], bf1, c1, 0, 0, 0);
            }
        }
        // fused layer 4: p[j] += sum_i relu(a3[i][j] + b3[i]) * w4[i] over this wave's i-slice
        {
            float p0 = 0.0f, p1 = 0.0f;
#pragma unroll
            for (int g = 0; g < 4; ++g) {
                const int i0 = mi * 32 + 8 * g + 4 * hi;
                const floatx4 b3v = *(const floatx4*)(&b3s[i0]);
                const floatx4 w4v = *(const floatx4*)(&w4s[i0]);
#pragma unroll
                for (int r = 0; r < 4; ++r) {
                    p0 = fmaf(fmaxf(c0[4 * g + r] + b3v[r], 0.0f), w4v[r], p0);
                    p1 = fmaf(fmaxf(c1[4 * g + r] + b3v[r], 0.0f), w4v[r], p1);
                }
            }
            p0 += __shfl_xor(p0, 32);
            p1 += __shfl_xor(p1, 32);
            if (hi == 0) {
                atomicAdd(&posum[j0], p0);
                atomicAdd(&posum[j0 + 32], p1);
            }
        }
        // L1 for tile t+1 -> A1 (A1[t] fully consumed by P1's MFMAs before the barrier)
        if (t + 1 < NTILE) {
            const int tb = (t + 1) * MT;
#pragma unroll
            for (int rr = 0; rr < 4; ++rr) {
                int lr = tb + rb + rr;
                int lrc = lr < RPB ? lr : RPB - 1;
                unsigned bbl = (unsigned)lrc / 51u;
                int ss = lrc - (int)bbl * 51;
                float X = xs[bbl] * ts[ss], hb = hs[bbl];
                unsigned vv[4];
#pragma unroll
                for (int e2 = 0; e2 < 4; ++e2) {
                    float u0 = fmaxf(fmaf(X, w1s[k0 + 2 * e2], fmaf(hb, w1s[HID + k0 + 2 * e2], b1s[k0 + 2 * e2])), 0.0f);
                    float u1 = fmaxf(fmaf(X, w1s[k0 + 2 * e2 + 1], fmaf(hb, w1s[HID + k0 + 2 * e2 + 1], b1s[k0 + 2 * e2 + 1])), 0.0f);
                    vv[e2] = pk_bf16(u0, u1);
                }
                *(uint4*)(&A1[rb + rr][k0]) = make_uint4(vv[0], vv[1], vv[2], vv[3]);
            }
        }
        __syncthreads();
    }

    // final consume of last tile's partials
    if (tid < MT) {
        int lr = (NTILE - 1) * MT + tid;
        if (lr < RPB) {
            float u = posum[tid] + b4v;
            unsigned bbl = (unsigned)lr / 51u;
            int ss = lr - (int)bbl * 51;
            float dz = u > 0.0f ? u + 1.0f : __expf(u);
            atomicAdd(&osum[bbl], dz * fs[ss]);
        }
    }
    __syncthreads();

    if (tid < BPB) out[blockIdx.x * BPB + tid] = hs[tid] + osum[tid] * xs[tid];
}

extern "C" void kernel_launch(void* const* d_in, const int* in_sizes, int n_in,
                              void* d_out, int out_size, void* d_ws, size_t ws_size,
                              hipStream_t stream) {
    const float* x  = (const float*)d_in[0];
    const float* h  = (const float*)d_in[1];
    const float* w1 = (const float*)d_in[2];
    const float* b1 = (const float*)d_in[3];
    const float* w2 = (const float*)d_in[4];
    const float* b2 = (const float*)d_in[5];
    const float* w3 = (const float*)d_in[6];
    const float* b3 = (const float*)d_in[7];
    const float* w4 = (const float*)d_in[8];
    const float* b4 = (const float*)d_in[9];
    float* out = (float*)d_out;

    monotonic_fused<<<GRID, 512, 0, stream>>>(x, h, w1, b1, w2, b2, w3, b3, w4, b4, out);
}

// Round 4
// 177.368 us; speedup vs baseline: 2.1613x; 1.1638x over previous
//
#include <hip/hip_runtime.h>
#include <hip/hip_bf16.h>

#define NSTEP 50
#define S51 51
#define HID 128
#define MT 64                  // rows per tile
#define BPB 8                  // batch elems per block (block owns them -> no global atomics)
#define RPB (BPB * S51)        // 408 valid rows per block
#define NTILE 7                // ceil(408/64): 448 rows, 40 masked
#define GRID (16384 / BPB)     // 2048 blocks
#define BLOCK 256              // 4 waves

typedef __attribute__((ext_vector_type(8))) short short8;
typedef __attribute__((ext_vector_type(4))) float floatx4;
typedef __attribute__((ext_vector_type(16))) float floatx16;

__device__ __forceinline__ unsigned pk_bf16(float a, float b) {
    __hip_bfloat162 t = __float22bfloat162_rn(make_float2(a, b));
    unsigned u;
    __builtin_memcpy(&u, &t, 4);
    return u;
}

// Swizzled activation layout: row-major 64x128 bf16, rows are 16 chunks of 16B,
// phys_chunk = chunk ^ (row & 15). No padding (A1+A2 = 32 KB), conflict-free for
// both the row-parallel writers and the MFMA B-operand readers.
__device__ __forceinline__ int sw_idx(int row, int chunk) {
    return row * HID + ((chunk ^ (row & 15)) << 3);   // in shorts
}

// 4 waves/block; wave wv owns hidden slice [wv*32, wv*32+32) as MFMA A-operand
// (W^T in registers, 8 frags x 4 VGPR x 2 layers). Each wave reads all 64 rows
// (2 j-tiles of 32) of the activation tile as B-operand. Layer4 fused into L3 accs.
__launch_bounds__(BLOCK, 4)
__global__ void monotonic_fused(const float* __restrict__ x, const float* __restrict__ h,
                                const float* __restrict__ w1, const float* __restrict__ b1,
                                const float* __restrict__ w2, const float* __restrict__ b2,
                                const float* __restrict__ w3, const float* __restrict__ b3,
                                const float* __restrict__ w4, const float* __restrict__ b4,
                                float* __restrict__ out) {
    __shared__ __align__(16) unsigned short A1[MT * HID];   // a1 (L1 out, L2 in), 16 KB
    __shared__ __align__(16) unsigned short A2[MT * HID];   // a2 (L2 out, L3 in), 16 KB
    __shared__ float w1s[2 * HID], b1s[HID], b2s[HID], b3s[HID], w4s[HID];
    __shared__ float fs[S51], ts[S51];
    __shared__ float xs[BPB], hs[BPB], osum[BPB];
    __shared__ float posum[MT];                              // per-row fused-L4 partials

    const int tid = threadIdx.x;
    const int lane = tid & 63;
    const int wv = tid >> 6;      // 0..3 = hidden 32-slice (mi)
    const int l31 = lane & 31;
    const int hi = lane >> 5;
    const int r1 = tid >> 2;          // L1 writer: row 0..63
    const int cb = (tid & 3) * 4;     // L1 writer: base chunk (4 chunks = 32 k-cols)

    // ---- stage small tensors ----
    w1s[tid] = w1[tid];               // 256 threads = 256 elems exactly
    if (tid < HID) {
        b1s[tid] = b1[tid]; b2s[tid] = b2[tid]; b3s[tid] = b3[tid]; w4s[tid] = w4[tid];
    }
    if (tid < MT) posum[tid] = 0.0f;
    if (tid < BPB) {
        xs[tid] = x[blockIdx.x * BPB + tid];
        hs[tid] = h[blockIdx.x * BPB + tid];
        osum[tid] = 0.0f;
    }
    if (tid < S51) {
        // Faithful port of compute_cc_weights (verified R1-R3, absmax 0.031)
        const float PI50 = 0.06283185307179586f;  // pi/50
        float acc = 1.0f;
        for (int i = 2; i <= 50; i += 2) {
            int m = (i * tid) % 100;  // exact argument reduction
            acc += (2.0f / (1.0f - (float)(i * i))) * cosf((float)m * PI50);
        }
        float ccw = acc * 0.04f * ((tid == 0 || tid == NSTEP) ? 0.5f : 1.0f);
        fs[tid] = ccw * 0.5f;                               // folds the (x-x0)*0.5 factor
        ts[tid] = (cosf((float)tid * PI50) + 1.0f) * 0.5f;  // (steps+1)/2
    }
    const float b4v = b4[0];

    // ---- gather W2^T / W3^T A-operand fragments (coalesced over l31) ----
    // frag[kc] elem e = W[kc*16 + hi*8 + e][wv*32 + l31]
    short8 w2f[8], w3f[8];
    {
        const int irow = wv * 32 + l31;
#pragma unroll
        for (int kc = 0; kc < 8; ++kc) {
            const int kb = kc * 16 + hi * 8;
            union { short8 s; unsigned u[4]; } c2, c3;
#pragma unroll
            for (int e2 = 0; e2 < 4; ++e2) {
                c2.u[e2] = pk_bf16(w2[(kb + 2 * e2) * HID + irow], w2[(kb + 2 * e2 + 1) * HID + irow]);
                c3.u[e2] = pk_bf16(w3[(kb + 2 * e2) * HID + irow], w3[(kb + 2 * e2 + 1) * HID + irow]);
            }
            w2f[kc] = c2.s;
            w3f[kc] = c3.s;
        }
    }
    __syncthreads();

    // ---- L1 for tile 0 -> A1 ----
    {
        int lrc = r1;  // tile 0 rows all valid
        unsigned bbl = (unsigned)lrc / 51u;
        int ss = lrc - (int)bbl * 51;
        float X = xs[bbl] * ts[ss], hb = hs[bbl];
#pragma unroll
        for (int cc = 0; cc < 4; ++cc) {
            const int kc0 = (cb + cc) * 8;
            unsigned vv[4];
#pragma unroll
            for (int e2 = 0; e2 < 4; ++e2) {
                float u0 = fmaxf(fmaf(X, w1s[kc0 + 2 * e2], fmaf(hb, w1s[HID + kc0 + 2 * e2], b1s[kc0 + 2 * e2])), 0.0f);
                float u1 = fmaxf(fmaf(X, w1s[kc0 + 2 * e2 + 1], fmaf(hb, w1s[HID + kc0 + 2 * e2 + 1], b1s[kc0 + 2 * e2 + 1])), 0.0f);
                vv[e2] = pk_bf16(u0, u1);
            }
            *(uint4*)(&A1[sw_idx(r1, cb + cc)]) = make_uint4(vv[0], vv[1], vv[2], vv[3]);
        }
    }
    __syncthreads();

    for (int t = 0; t < NTILE; ++t) {
        // ================= P1: layer 2 (read A1), bias pre-loaded in acc =================
        floatx16 a0, a1;
#pragma unroll
        for (int g = 0; g < 4; ++g) {
            const floatx4 bb = *(const floatx4*)(&b2s[wv * 32 + 8 * g + 4 * hi]);
#pragma unroll
            for (int rr = 0; rr < 4; ++rr) { a0[4 * g + rr] = bb[rr]; a1[4 * g + rr] = bb[rr]; }
        }
#pragma unroll
        for (int kc = 0; kc < 8; ++kc) {
            short8 f0 = *(const short8*)(&A1[sw_idx(l31, kc * 2 + hi)]);
            short8 f1 = *(const short8*)(&A1[sw_idx(l31 + 32, kc * 2 + hi)]);
            a0 = __builtin_amdgcn_mfma_f32_32x32x16_bf16(w2f[kc], f0, a0, 0, 0, 0);
            a1 = __builtin_amdgcn_mfma_f32_32x32x16_bf16(w2f[kc], f1, a1, 0, 0, 0);
        }
        // consume previous tile's fused-L4 partials while MFMAs drain
        if (t > 0 && tid < MT) {
            int lr = (t - 1) * MT + tid;
            float u = posum[tid] + b4v;
            posum[tid] = 0.0f;
            if (lr < RPB) {
                unsigned bbl = (unsigned)lr / 51u;
                int ss = lr - (int)bbl * 51;
                float dz = u > 0.0f ? u + 1.0f : __expf(u);  // elu(u)+1
                atomicAdd(&osum[bbl], dz * fs[ss]);
            }
        }
        // epilogue: relu(acc) -> A2 (bias already in acc)
#pragma unroll
        for (int g = 0; g < 4; ++g) {
            const int chI = wv * 4 + g;
            float v0 = fmaxf(a0[4 * g + 0], 0.0f), v1 = fmaxf(a0[4 * g + 1], 0.0f);
            float v2 = fmaxf(a0[4 * g + 2], 0.0f), v3 = fmaxf(a0[4 * g + 3], 0.0f);
            *(unsigned long long*)(&A2[sw_idx(l31, chI) + 4 * hi]) =
                ((unsigned long long)pk_bf16(v2, v3) << 32) | (unsigned long long)pk_bf16(v0, v1);
            v0 = fmaxf(a1[4 * g + 0], 0.0f); v1 = fmaxf(a1[4 * g + 1], 0.0f);
            v2 = fmaxf(a1[4 * g + 2], 0.0f); v3 = fmaxf(a1[4 * g + 3], 0.0f);
            *(unsigned long long*)(&A2[sw_idx(l31 + 32, chI) + 4 * hi]) =
                ((unsigned long long)pk_bf16(v2, v3) << 32) | (unsigned long long)pk_bf16(v0, v1);
        }
        __syncthreads();

        // ================= P2: layer 3 (read A2) + fused layer 4 + L1(t+1) =================
        floatx16 c0, c1;
#pragma unroll
        for (int g = 0; g < 4; ++g) {
            const floatx4 bb = *(const floatx4*)(&b3s[wv * 32 + 8 * g + 4 * hi]);
#pragma unroll
            for (int rr = 0; rr < 4; ++rr) { c0[4 * g + rr] = bb[rr]; c1[4 * g + rr] = bb[rr]; }
        }
#pragma unroll
        for (int kc = 0; kc < 8; ++kc) {
            short8 f0 = *(const short8*)(&A2[sw_idx(l31, kc * 2 + hi)]);
            short8 f1 = *(const short8*)(&A2[sw_idx(l31 + 32, kc * 2 + hi)]);
            c0 = __builtin_amdgcn_mfma_f32_32x32x16_bf16(w3f[kc], f0, c0, 0, 0, 0);
            c1 = __builtin_amdgcn_mfma_f32_32x32x16_bf16(w3f[kc], f1, c1, 0, 0, 0);
        }
        // fused layer 4: p[j] += sum_i relu(a3[i][j]) * w4[i] (bias pre-added in acc)
        {
            float p0 = 0.0f, p1 = 0.0f;
#pragma unroll
            for (int g = 0; g < 4; ++g) {
                const floatx4 w4v = *(const floatx4*)(&w4s[wv * 32 + 8 * g + 4 * hi]);
#pragma unroll
                for (int rr = 0; rr < 4; ++rr) {
                    p0 = fmaf(fmaxf(c0[4 * g + rr], 0.0f), w4v[rr], p0);
                    p1 = fmaf(fmaxf(c1[4 * g + rr], 0.0f), w4v[rr], p1);
                }
            }
            p0 += __shfl_xor(p0, 32);
            p1 += __shfl_xor(p1, 32);
            if (hi == 0) {
                atomicAdd(&posum[l31], p0);
                atomicAdd(&posum[l31 + 32], p1);
            }
        }
        // L1 for tile t+1 -> A1 (A1[t] fully consumed by P1's MFMAs before the barrier)
        if (t + 1 < NTILE) {
            int lr = (t + 1) * MT + r1;
            int lrc = lr < RPB ? lr : RPB - 1;
            unsigned bbl = (unsigned)lrc / 51u;
            int ss = lrc - (int)bbl * 51;
            float X = xs[bbl] * ts[ss], hb = hs[bbl];
#pragma unroll
            for (int cc = 0; cc < 4; ++cc) {
                const int kc0 = (cb + cc) * 8;
                unsigned vv[4];
#pragma unroll
                for (int e2 = 0; e2 < 4; ++e2) {
                    float u0 = fmaxf(fmaf(X, w1s[kc0 + 2 * e2], fmaf(hb, w1s[HID + kc0 + 2 * e2], b1s[kc0 + 2 * e2])), 0.0f);
                    float u1 = fmaxf(fmaf(X, w1s[kc0 + 2 * e2 + 1], fmaf(hb, w1s[HID + kc0 + 2 * e2 + 1], b1s[kc0 + 2 * e2 + 1])), 0.0f);
                    vv[e2] = pk_bf16(u0, u1);
                }
                *(uint4*)(&A1[sw_idx(r1, cb + cc)]) = make_uint4(vv[0], vv[1], vv[2], vv[3]);
            }
        }
        __syncthreads();
    }

    // final consume of last tile's partials
    if (tid < MT) {
        int lr = (NTILE - 1) * MT + tid;
        if (lr < RPB) {
            float u = posum[tid] + b4v;
            unsigned bbl = (unsigned)lr / 51u;
            int ss = lr - (int)bbl * 51;
            float dz = u > 0.0f ? u + 1.0f : __expf(u);
            atomicAdd(&osum[bbl], dz * fs[ss]);
        }
    }
    __syncthreads();

    if (tid < BPB) out[blockIdx.x * BPB + tid] = hs[tid] + osum[tid] * xs[tid];
}

extern "C" void kernel_launch(void* const* d_in, const int* in_sizes, int n_in,
                              void* d_out, int out_size, void* d_ws, size_t ws_size,
                              hipStream_t stream) {
    const float* x  = (const float*)d_in[0];
    const float* h  = (const float*)d_in[1];
    const float* w1 = (const float*)d_in[2];
    const float* b1 = (const float*)d_in[3];
    const float* w2 = (const float*)d_in[4];
    const float* b2 = (const float*)d_in[5];
    const float* w3 = (const float*)d_in[6];
    const float* b3 = (const float*)d_in[7];
    const float* w4 = (const float*)d_in[8];
    const float* b4 = (const float*)d_in[9];
    float* out = (float*)d_out;

    monotonic_fused<<<GRID, BLOCK, 0, stream>>>(x, h, w1, b1, w2, b2, w3, b3, w4, b4, out);
}